// Round 1
// baseline (41.421 us; speedup 1.0000x reference)
//
#include <hip/hip_runtime.h>

#define BS 1024
#define D 1024
#define NEG 32
#define TEMP_INV 20.0f
#define CLS_WEIGHT 0.2f
#define EPS 1e-8f

__global__ __launch_bounds__(256) void cls_contrast_loss_kernel(
    const float* __restrict__ q,      // [BS, D]
    const float* __restrict__ p,      // [BS, D]
    const float* __restrict__ neg,    // [BS*NEG, D]
    float* __restrict__ out)          // [1]
{
    const int b    = blockIdx.x;
    const int tid  = threadIdx.x;
    const int lane = tid & 63;
    const int wave = tid >> 6;

    __shared__ float q_sh[D];          // 4 KB
    __shared__ float sim_sh[33];
    __shared__ float qn_partial[4];

    // ---- Phase 1: load q row into LDS, compute ||q||^2 ----
    const float4* q4 = reinterpret_cast<const float4*>(q + (size_t)b * D);
    float4 qv = q4[tid];                               // 256 threads x float4 = 1024 floats
    reinterpret_cast<float4*>(q_sh)[tid] = qv;
    float qn = qv.x*qv.x + qv.y*qv.y + qv.z*qv.z + qv.w*qv.w;
    #pragma unroll
    for (int off = 32; off > 0; off >>= 1)
        qn += __shfl_down(qn, off);
    if (lane == 0) qn_partial[wave] = qn;
    __syncthreads();
    const float q_norm = fmaxf(sqrtf(qn_partial[0] + qn_partial[1] +
                                     qn_partial[2] + qn_partial[3]), EPS);

    // ---- Phase 2: 33 similarity values (v=0 -> pos, v>=1 -> neg v-1) ----
    const float4* qs4 = reinterpret_cast<const float4*>(q_sh);
    for (int vidx = wave; vidx < 33; vidx += 4) {
        const float* vec = (vidx == 0)
            ? (p + (size_t)b * D)
            : (neg + ((size_t)b * NEG + (size_t)(vidx - 1)) * (size_t)D);
        const float4* vec4 = reinterpret_cast<const float4*>(vec);
        float s = 0.f, nn = 0.f;
        #pragma unroll
        for (int j = 0; j < 4; ++j) {
            const int i4 = lane + j * 64;              // coalesced: 64 lanes x 16B
            float4 a  = vec4[i4];
            float4 qq = qs4[i4];
            s  += a.x*qq.x + a.y*qq.y + a.z*qq.z + a.w*qq.w;
            nn += a.x*a.x  + a.y*a.y  + a.z*a.z  + a.w*a.w;
        }
        #pragma unroll
        for (int off = 32; off > 0; off >>= 1) {
            s  += __shfl_down(s,  off);
            nn += __shfl_down(nn, off);
        }
        if (lane == 0) {
            const float n_norm = fmaxf(sqrtf(nn), EPS);
            sim_sh[vidx] = (s / (q_norm * n_norm)) * TEMP_INV;
        }
    }
    __syncthreads();

    // ---- Phase 3: row loss = logsumexp(sim) - sim[0]; accumulate mean ----
    if (tid == 0) {
        float m = sim_sh[0];
        #pragma unroll
        for (int i = 1; i < 33; ++i) m = fmaxf(m, sim_sh[i]);
        float sum = 0.f;
        #pragma unroll
        for (int i = 0; i < 33; ++i) sum += expf(sim_sh[i] - m);
        const float lse = m + logf(sum);
        const float row_loss = lse - sim_sh[0];
        atomicAdd(out, row_loss * (CLS_WEIGHT / (float)BS));
    }
}

extern "C" void kernel_launch(void* const* d_in, const int* in_sizes, int n_in,
                              void* d_out, int out_size, void* d_ws, size_t ws_size,
                              hipStream_t stream) {
    const float* q   = (const float*)d_in[0];   // text_embeddings   [BS*D]
    const float* p   = (const float*)d_in[1];   // text_pos_embeddings [BS*D]
    const float* neg = (const float*)d_in[2];   // text_neg_embeddings [BS*NEG*D]
    float* out = (float*)d_out;

    // d_out is poisoned (0xAA) and never re-poisoned between replays:
    // zero it every call so the atomic accumulation starts clean.
    hipMemsetAsync(out, 0, (size_t)out_size * sizeof(float), stream);

    cls_contrast_loss_kernel<<<BS, 256, 0, stream>>>(q, p, neg, out);
}

// Round 2
// 31.439 us; speedup vs baseline: 1.3175x; 1.3175x over previous
//
#include <hip/hip_runtime.h>

#define BS 1024
#define D 1024
#define NEG 32
#define TEMP_INV 20.0f
#define CLS_WEIGHT 0.2f
#define EPS 1e-8f

// One block (1024 threads = 16 waves) per batch row.
// Each wave holds the FULL q row in 16 VGPRs (same lane-indices for every
// vector), computes ||q||^2 wave-locally, and owns 2 similarity vectors
// (wave 0 additionally owns the 33rd). Shuffle reductions for all
// accumulators are interleaved so the 6 levels pipeline instead of
// serializing per-vector.
__global__ __launch_bounds__(1024) void cls_sim_kernel(
    const float* __restrict__ q,      // [BS, D]
    const float* __restrict__ p,      // [BS, D]
    const float* __restrict__ neg,    // [BS*NEG, D]
    float* __restrict__ row_loss)     // [BS]
{
    const int b    = blockIdx.x;
    const int tid  = threadIdx.x;
    const int lane = tid & 63;
    const int wave = tid >> 6;        // 0..15

    __shared__ float sim_sh[33];

    // ---- q row into registers (wave-redundant; L1-resident after wave 0) ----
    const float4* q4 = reinterpret_cast<const float4*>(q + (size_t)b * D);
    float4 qv[4];
    #pragma unroll
    for (int j = 0; j < 4; ++j) qv[j] = q4[lane + j * 64];

    // ---- vector assignment: wave w -> {w, w+16}, wave 0 also {32} ----
    const int v0 = wave;
    const int v1 = wave + 16;
    const bool has2 = (wave == 0);

    const float4* p0 = reinterpret_cast<const float4*>(
        (v0 == 0) ? (p + (size_t)b * D)
                  : (neg + ((size_t)b * NEG + (size_t)(v0 - 1)) * (size_t)D));
    const float4* p1 = reinterpret_cast<const float4*>(
        neg + ((size_t)b * NEG + (size_t)(v1 - 1)) * (size_t)D);
    const float4* p2 = reinterpret_cast<const float4*>(
        neg + ((size_t)b * NEG + 31) * (size_t)D);

    float qn = 0.f;
    float s0 = 0.f, n0 = 0.f, s1 = 0.f, n1 = 0.f, s2 = 0.f, n2 = 0.f;

    #pragma unroll
    for (int j = 0; j < 4; ++j) {
        const int i4 = lane + j * 64;             // coalesced 16B/lane
        const float4 a0 = p0[i4];
        const float4 a1 = p1[i4];
        const float4 qq = qv[j];
        qn += qq.x*qq.x + qq.y*qq.y + qq.z*qq.z + qq.w*qq.w;
        s0 += a0.x*qq.x + a0.y*qq.y + a0.z*qq.z + a0.w*qq.w;
        n0 += a0.x*a0.x + a0.y*a0.y + a0.z*a0.z + a0.w*a0.w;
        s1 += a1.x*qq.x + a1.y*qq.y + a1.z*qq.z + a1.w*qq.w;
        n1 += a1.x*a1.x + a1.y*a1.y + a1.z*a1.z + a1.w*a1.w;
    }
    if (has2) {
        #pragma unroll
        for (int j = 0; j < 4; ++j) {
            const int i4 = lane + j * 64;
            const float4 a2 = p2[i4];
            const float4 qq = qv[j];
            s2 += a2.x*qq.x + a2.y*qq.y + a2.z*qq.z + a2.w*qq.w;
            n2 += a2.x*a2.x + a2.y*a2.y + a2.z*a2.z + a2.w*a2.w;
        }
    }

    // ---- interleaved wave reduction (independent shuffles per level) ----
    #pragma unroll
    for (int off = 32; off > 0; off >>= 1) {
        qn += __shfl_down(qn, off);
        s0 += __shfl_down(s0, off);
        n0 += __shfl_down(n0, off);
        s1 += __shfl_down(s1, off);
        n1 += __shfl_down(n1, off);
    }
    if (has2) {
        #pragma unroll
        for (int off = 32; off > 0; off >>= 1) {
            s2 += __shfl_down(s2, off);
            n2 += __shfl_down(n2, off);
        }
    }

    if (lane == 0) {
        const float q_norm = fmaxf(sqrtf(qn), EPS);
        sim_sh[v0] = (s0 / (q_norm * fmaxf(sqrtf(n0), EPS))) * TEMP_INV;
        sim_sh[v1] = (s1 / (q_norm * fmaxf(sqrtf(n1), EPS))) * TEMP_INV;
        if (has2)
            sim_sh[32] = (s2 / (q_norm * fmaxf(sqrtf(n2), EPS))) * TEMP_INV;
    }
    __syncthreads();

    // ---- wave 0: parallel 33-element logsumexp, write per-row loss ----
    if (wave == 0) {
        const float x = (lane < 33) ? sim_sh[lane] : -1e30f;
        float m = x;
        #pragma unroll
        for (int off = 32; off > 0; off >>= 1)
            m = fmaxf(m, __shfl_down(m, off));
        m = __shfl(m, 0);
        float e = (lane < 33) ? expf(x - m) : 0.f;
        #pragma unroll
        for (int off = 32; off > 0; off >>= 1)
            e += __shfl_down(e, off);
        if (lane == 0)
            row_loss[b] = (m + logf(e)) - sim_sh[0];
    }
}

// Single-block reduction of the 1024 per-row losses; overwrites out[0]
// directly (no memset, no atomics needed).
__global__ __launch_bounds__(256) void cls_loss_reduce_kernel(
    const float* __restrict__ row_loss, float* __restrict__ out)
{
    const int tid  = threadIdx.x;
    const int lane = tid & 63;
    const int wave = tid >> 6;

    __shared__ float partial[4];

    const float4 v = reinterpret_cast<const float4*>(row_loss)[tid];
    float s = v.x + v.y + v.z + v.w;
    #pragma unroll
    for (int off = 32; off > 0; off >>= 1)
        s += __shfl_down(s, off);
    if (lane == 0) partial[wave] = s;
    __syncthreads();
    if (tid == 0) {
        const float total = partial[0] + partial[1] + partial[2] + partial[3];
        out[0] = total * (CLS_WEIGHT / (float)BS);
    }
}

extern "C" void kernel_launch(void* const* d_in, const int* in_sizes, int n_in,
                              void* d_out, int out_size, void* d_ws, size_t ws_size,
                              hipStream_t stream) {
    const float* q   = (const float*)d_in[0];   // text_embeddings     [BS*D]
    const float* p   = (const float*)d_in[1];   // text_pos_embeddings [BS*D]
    const float* neg = (const float*)d_in[2];   // text_neg_embeddings [BS*NEG*D]
    float* out      = (float*)d_out;
    float* row_loss = (float*)d_ws;             // BS floats of scratch

    cls_sim_kernel<<<BS, 1024, 0, stream>>>(q, p, neg, row_loss);
    cls_loss_reduce_kernel<<<1, 256, 0, stream>>>(row_loss, out);
}